// Round 10
// baseline (309.559 us; speedup 1.0000x reference)
//
#include <hip/hip_runtime.h>
#include <hip/hip_bf16.h>

#define N_NODES 50000
#define E_EDGES 400000
#define IN_CH   256
#define HEADS   4
#define OUT_CH  64
#define HID     256
#define ALPHA   0.2f
#define LN_EPS  1e-5f

using f32x16 = __attribute__((ext_vector_type(16))) float;
using bf16x8 = __attribute__((ext_vector_type(8))) short;   // 8 bf16 (4 VGPRs)
using u16x8  = __attribute__((ext_vector_type(8))) unsigned short;
using u16x4  = __attribute__((ext_vector_type(4))) unsigned short;

typedef __attribute__((address_space(3))) void* lds_vp;
typedef const __attribute__((address_space(1))) void* gbl_vp;

__device__ __forceinline__ unsigned short f2bf(float f) {
    __hip_bfloat16 b = __float2bfloat16(f);
    return *(unsigned short*)&b;
}
__device__ __forceinline__ float bf2f(unsigned short u) {
    __hip_bfloat16 b = *(__hip_bfloat16*)&u;
    return __bfloat162float(b);
}

// ------------------------------------------------------------------ prep
__global__ __launch_bounds__(256) void prep_kernel(
    const float* __restrict__ W, const float* __restrict__ ffn_w,
    unsigned short* __restrict__ Wt, unsigned short* __restrict__ Ft)
{
    int i = blockIdx.x * 256 + threadIdx.x;
    if (i < 65536) {
        int n = i >> 8, k = i & 255;
        Wt[i] = f2bf(W[k * 256 + n]);
    } else {
        int j = i - 65536;
        int n = j >> 8, k = j & 255;
        Ft[j] = f2bf(ffn_w[k * 256 + n]);
    }
}

// ------------------------------------------------------------------ B-resident GEMM (GEMM1)
// C[M,256] = A[M,256] @ B; Bt[n][k] bf16 staged entirely in LDS (128 KiB) once.
// One barrier; each wave independently streams a 32-row A strip with a 4-deep
// register prefetch pipeline and mfma_f32_32x32x16_bf16.
template<bool A_IS_F32, bool RELU_BIAS>
__global__ __launch_bounds__(512, 2) void gemm_bres(
    const void* __restrict__ Av, const unsigned short* __restrict__ Bt,
    const float* __restrict__ bias, void* __restrict__ Cv, int M)
{
    __shared__ unsigned short Bs[256 * 256];   // 128 KiB

    const int tid = threadIdx.x;
    const int lane = tid & 63, wid = tid >> 6;

    #pragma unroll
    for (int i = 0; i < 16; i++) {
        int d = i * 512 + tid;                 // 16B-chunk id, 0..8191
        int n = d >> 5, cp = d & 31;
        int cs = cp ^ (n & 31);                // inverse swizzle on source
        const unsigned short* g = Bt + (size_t)n * 256 + cs * 8;
        __builtin_amdgcn_global_load_lds((gbl_vp)g, (lds_vp)&Bs[(size_t)d * 8],
                                         16, 0, 0);
    }
    __syncthreads();

    const int strip = wid * 256 + blockIdx.x;  // interleaved for CU balance
    const int r0 = strip * 32;
    if (r0 >= M) return;

    const int q5 = lane & 31, kg = lane >> 5;
    const int rowc = min(r0 + q5, M - 1);      // clamped for tail strip

    f32x16 acc[8] = {};

    const float* Af = (const float*)Av;
    const unsigned short* Ab = (const unsigned short*)Av;

    float4 pa[4], pb[4]; u16x8 pc[4];
    auto loadA = [&](int t, int slot) {
        if (A_IS_F32) {
            const float* p = Af + (size_t)rowc * 256 + t * 16 + kg * 8;
            pa[slot] = *(const float4*)p; pb[slot] = *(const float4*)(p + 4);
        } else {
            pc[slot] = *(const u16x8*)(Ab + (size_t)rowc * 256 + t * 16 + kg * 8);
        }
    };
    loadA(0, 0); loadA(1, 1); loadA(2, 2); loadA(3, 3);

    #pragma unroll
    for (int t = 0; t < 16; t++) {
        const int slot = t & 3;
        bf16x8 af;
        if (A_IS_F32) {
            union { unsigned int u[4]; bf16x8 v; } cv;
            cv.u[0] = (unsigned)f2bf(pa[slot].x) | ((unsigned)f2bf(pa[slot].y) << 16);
            cv.u[1] = (unsigned)f2bf(pa[slot].z) | ((unsigned)f2bf(pa[slot].w) << 16);
            cv.u[2] = (unsigned)f2bf(pb[slot].x) | ((unsigned)f2bf(pb[slot].y) << 16);
            cv.u[3] = (unsigned)f2bf(pb[slot].z) | ((unsigned)f2bf(pb[slot].w) << 16);
            af = cv.v;
        } else {
            union { u16x8 u; bf16x8 v; } cv; cv.u = pc[slot]; af = cv.v;
        }
        if (t + 4 < 16) loadA(t + 4, slot);
        #pragma unroll
        for (int n = 0; n < 8; n++) {
            const bf16x8 bf = *(const bf16x8*)((const char*)Bs +
                (size_t)(n * 32 + q5) * 512 + (((t * 2 + kg) ^ q5) * 16));
            acc[n] = __builtin_amdgcn_mfma_f32_32x32x16_bf16(af, bf, acc[n], 0, 0, 0);
        }
    }

    // D layout: col = lane&31, row = (reg&3)+8*(reg>>2)+4*kg  (verified)
    #pragma unroll
    for (int n = 0; n < 8; n++) {
        int gc = n * 32 + q5;
        float bv = RELU_BIAS ? bias[gc] : 0.f;
        #pragma unroll
        for (int reg = 0; reg < 16; reg++) {
            int rl = (reg & 3) + 8 * (reg >> 2) + 4 * kg;
            int gr = r0 + rl;
            if (gr >= M) continue;
            float v = acc[n][reg];
            if (RELU_BIAS) {
                v += bv; v = v > 0.f ? v : 0.f;
                ((float*)Cv)[(size_t)gr * 256 + gc] = v;
            } else {
                ((unsigned short*)Cv)[(size_t)gr * 256 + gc] = f2bf(v);
            }
        }
    }
}

// ------------------------------------------------------------------ scores
__global__ __launch_bounds__(256) void scores_kernel(
    const unsigned short* __restrict__ Wh, const float* __restrict__ attn_fc,
    float* __restrict__ s_src, float* __restrict__ s_dst)
{
    const int lane = threadIdx.x & 63, wid = threadIdx.x >> 6;
    const int n = blockIdx.x * 4 + wid;
    const int h = lane >> 4;
    const int d0 = 4 * (lane & 15);
    u16x4 w = *(const u16x4*)(Wh + (size_t)n * HID + 4 * lane);
    float ps = 0.f, pd = 0.f;
    #pragma unroll
    for (int q = 0; q < 4; q++) {
        float wf = bf2f(w[q]);
        ps += wf * attn_fc[h * 128 + d0 + q];
        pd += wf * attn_fc[h * 128 + 64 + d0 + q];
    }
    #pragma unroll
    for (int off = 8; off; off >>= 1) {
        ps += __shfl_xor(ps, off, 16);
        pd += __shfl_xor(pd, off, 16);
    }
    if ((lane & 15) == 0) {
        s_src[n * HEADS + h] = ps;
        s_dst[n * HEADS + h] = pd;
    }
}

// ------------------------------------------------------------------ histogram
__global__ void hist_kernel(const int* __restrict__ erow, int* __restrict__ counts) {
    int e = blockIdx.x * blockDim.x + threadIdx.x;
    if (e < E_EDGES) atomicAdd(&counts[erow[e]], 1);
}

// ------------------------------------------------------------------ 3-pass scan
__global__ __launch_bounds__(256) void scanA_kernel(
    const int* __restrict__ counts, int* __restrict__ bsum)
{
    const int b = blockIdx.x, tid = threadIdx.x;
    int i0 = b * 512 + tid;
    int v = 0;
    if (i0 < N_NODES) v += counts[i0];
    if (i0 + 256 < N_NODES) v += counts[i0 + 256];
    #pragma unroll
    for (int off = 32; off; off >>= 1) v += __shfl_xor(v, off, 64);
    __shared__ int ws[4];
    if ((tid & 63) == 0) ws[tid >> 6] = v;
    __syncthreads();
    if (tid == 0) bsum[b] = ws[0] + ws[1] + ws[2] + ws[3];
}

__global__ __launch_bounds__(128) void scanB_kernel(
    const int* __restrict__ bsum, int* __restrict__ bscan, int nb)
{
    const int tid = threadIdx.x;
    const int lane = tid & 63, wid = tid >> 6;
    int val = (tid < nb) ? bsum[tid] : 0;
    int x = val;
    #pragma unroll
    for (int off = 1; off < 64; off <<= 1) {
        int y = __shfl_up(x, off, 64);
        if (lane >= off) x += y;
    }
    __shared__ int w0;
    if (tid == 63) w0 = x;
    __syncthreads();
    if (wid == 1) x += w0;
    if (tid < nb) bscan[tid] = x - val;
}

__global__ __launch_bounds__(512) void scanC_kernel(
    const int* __restrict__ counts, const int* __restrict__ bscan,
    int* __restrict__ offsets, int* __restrict__ cursor)
{
    const int b = blockIdx.x, tid = threadIdx.x;
    const int lane = tid & 63, wid = tid >> 6;
    const int i = b * 512 + tid;
    int v = (i < N_NODES) ? counts[i] : 0;
    int x = v;
    #pragma unroll
    for (int off = 1; off < 64; off <<= 1) {
        int y = __shfl_up(x, off, 64);
        if (lane >= off) x += y;
    }
    __shared__ int ws[8];
    if (lane == 63) ws[wid] = x;
    __syncthreads();
    if (wid == 0 && lane < 8) {
        int s = ws[lane];
        #pragma unroll
        for (int off = 1; off < 8; off <<= 1) {
            int y = __shfl_up(s, off, 8);
            if ((lane & 7) >= off) s += y;
        }
        ws[lane] = s;
    }
    __syncthreads();
    int prefix = (wid ? ws[wid - 1] : 0) + bscan[b];
    int excl = prefix + x - v;
    if (i < N_NODES) { offsets[i] = excl; cursor[i] = excl; }
    if (i == N_NODES - 1) offsets[N_NODES] = excl + v;
}

// ------------------------------------------------------------------ scatter + weight precompute
__global__ __launch_bounds__(256) void scatter_kernel(
    const int* __restrict__ erow, const int* __restrict__ ecol,
    const float* __restrict__ s_src, const float* __restrict__ s_dst,
    int* __restrict__ cursor, int* __restrict__ sorted_col,
    float4* __restrict__ sorted_w)
{
    int e = blockIdx.x * blockDim.x + threadIdx.x;
    if (e >= E_EDGES) return;
    int r = erow[e], c = ecol[e];
    float4 ss = ((const float4*)s_src)[r];
    float4 sd = ((const float4*)s_dst)[c];
    float sc[4] = {ss.x + sd.x, ss.y + sd.y, ss.z + sd.z, ss.w + sd.w};
    float4 w;
    float* wp = (float*)&w;
    #pragma unroll
    for (int h = 0; h < 4; h++) {
        float v = sc[h] > 0.f ? sc[h] : ALPHA * sc[h];
        wp[h] = __expf(v);
    }
    int pos = atomicAdd(&cursor[r], 1);
    sorted_col[pos] = c;
    sorted_w[pos] = w;
}

// ------------------------------------------------------------------ fused aggregate + LN + FFN GEMM
// Block = 512 thr (8 waves), 32 nodes.  Phase 0: async-stage Ft into LDS
// (no barrier).  Phase 1: R7-style per-node aggregation (pure registers,
// hides the stage): wave wid aggregates nodes n0+wid*4..+3; lane owns 8 cols
// (q5*8), 2 edges in parallel via lane halves; residual + LN; LN'd bf16 row
// written to swizzled LDS tile Hs.  Phase 2 (after one barrier): 8 waves do
// the 32x256x256 FFN GEMM; wave wid computes cols wid*32..+31 via 16x
// mfma_32x32x16 with A=Hs, B=FtS (both swizzle-read), relu+bias, f32 out.
__global__ __launch_bounds__(512) void agg_ffn_kernel(
    const unsigned short* __restrict__ Wh, const float* __restrict__ sorted_w,
    const int* __restrict__ offsets, const int* __restrict__ sorted_col,
    const float* __restrict__ ln_gamma, const float* __restrict__ ln_beta,
    const unsigned short* __restrict__ Ft, const float* __restrict__ ffn_b,
    float* __restrict__ out)
{
    __shared__ unsigned short FtS[256 * 256];  // 128 KiB
    __shared__ unsigned short Hs[32 * 256];    // 16 KiB LN'd rows

    const int tid = threadIdx.x;
    const int lane = tid & 63, wid = tid >> 6;

    // ---- phase 0: async Ft stage (completes under phase 1)
    #pragma unroll
    for (int i = 0; i < 16; i++) {
        int d = i * 512 + tid;
        int n = d >> 5, cp = d & 31;
        int cs = cp ^ (n & 31);
        const unsigned short* g = Ft + (size_t)n * 256 + cs * 8;
        __builtin_amdgcn_global_load_lds((gbl_vp)g, (lds_vp)&FtS[(size_t)d * 8],
                                         16, 0, 0);
    }

    // ---- phase 1: aggregation (R7 structure), 4 nodes per wave
    const int n0 = blockIdx.x * 32;
    const int p = lane >> 5;
    const int q5 = lane & 31;
    const int c0 = q5 * 8;
    const int h = q5 >> 3;

    for (int nd = 0; nd < 4; nd++) {
        const int lrow = wid * 4 + nd;
        const int n = n0 + lrow;
        if (n >= N_NODES) continue;
        const int beg = offsets[n], end = offsets[n + 1];

        float acc[8] = {};
        float wsum = 0.f;
        for (int base = beg; base < end; base += 64) {
            int cnt = min(64, end - base);
            int cv = (base + lane < end) ? sorted_col[base + lane] : 0;
            int jj = 0;
            #pragma unroll 2
            for (; jj + 2 <= cnt; jj += 2) {
                int c = __shfl(cv, jj + p, 64);
                float w = sorted_w[(size_t)(base + jj + p) * 4 + h];
                u16x8 r = *(const u16x8*)(Wh + (size_t)c * HID + c0);
                wsum += w;
                #pragma unroll
                for (int k = 0; k < 8; k++) acc[k] += w * bf2f(r[k]);
            }
            if (jj < cnt) {                    // odd tail edge: half-wave 0 only
                int c = __shfl(cv, jj, 64);
                if (p == 0) {
                    float w = sorted_w[(size_t)(base + jj) * 4 + h];
                    u16x8 r = *(const u16x8*)(Wh + (size_t)c * HID + c0);
                    wsum += w;
                    #pragma unroll
                    for (int k = 0; k < 8; k++) acc[k] += w * bf2f(r[k]);
                }
            }
        }
        wsum += __shfl_xor(wsum, 32, 64);
        #pragma unroll
        for (int k = 0; k < 8; k++) acc[k] += __shfl_xor(acc[k], 32, 64);

        u16x8 rr = *(const u16x8*)(Wh + (size_t)n * HID + c0);
        float inv_w = 1.f / (wsum + 1e-15f);
        float val[8];
        float s = 0.f;
        #pragma unroll
        for (int k = 0; k < 8; k++) {
            val[k] = acc[k] * inv_w + bf2f(rr[k]);
            s += val[k];
        }
        #pragma unroll
        for (int off = 16; off; off >>= 1) s += __shfl_xor(s, off, 64);
        float mu = s * (1.f / HID);
        float s2 = 0.f;
        #pragma unroll
        for (int k = 0; k < 8; k++) { float d = val[k] - mu; s2 += d * d; }
        #pragma unroll
        for (int off = 16; off; off >>= 1) s2 += __shfl_xor(s2, off, 64);
        float inv_std = rsqrtf(s2 * (1.f / HID) + LN_EPS);

        if (p == 0) {
            u16x8 o;
            #pragma unroll
            for (int k = 0; k < 8; k++)
                o[k] = f2bf((val[k] - mu) * inv_std * ln_gamma[c0 + k] + ln_beta[c0 + k]);
            // swizzled write: chunk q5 of row lrow -> q5 ^ lrow
            *(u16x8*)((char*)Hs + lrow * 512 + ((q5 ^ lrow) * 16)) = o;
        }
    }

    __syncthreads();   // drains Ft stage (vmcnt) + Hs writes (lgkmcnt)

    // ---- phase 2: FFN GEMM.  wave wid -> cols wid*32..+31, all 32 rows.
    const int kg = lane >> 5;
    f32x16 acc2 = {};
    #pragma unroll
    for (int t = 0; t < 16; t++) {
        const bf16x8 afr = *(const bf16x8*)((const char*)Hs +
            q5 * 512 + (((t * 2 + kg) ^ q5) * 16));
        const bf16x8 bfr = *(const bf16x8*)((const char*)FtS +
            (size_t)(wid * 32 + q5) * 512 + (((t * 2 + kg) ^ q5) * 16));
        acc2 = __builtin_amdgcn_mfma_f32_32x32x16_bf16(afr, bfr, acc2, 0, 0, 0);
    }
    const int gc = wid * 32 + q5;
    const float bv = ffn_b[gc];
    #pragma unroll
    for (int reg = 0; reg < 16; reg++) {
        int rl = (reg & 3) + 8 * (reg >> 2) + 4 * kg;
        int gr = n0 + rl;
        if (gr >= N_NODES) continue;
        float v = acc2[reg] + bv;
        v = v > 0.f ? v : 0.f;
        out[(size_t)gr * 256 + gc] = v;
    }
}

// ------------------------------------------------------------------ launch
extern "C" void kernel_launch(void* const* d_in, const int* in_sizes, int n_in,
                              void* d_out, int out_size, void* d_ws, size_t ws_size,
                              hipStream_t stream)
{
    const float* h        = (const float*)d_in[0];
    const int*   erow     = (const int*)  d_in[1];
    const int*   ecol     = (const int*)  d_in[2];
    const float* W        = (const float*)d_in[3];
    const float* attn_fc  = (const float*)d_in[4];
    const float* ln_gamma = (const float*)d_in[5];
    const float* ln_beta  = (const float*)d_in[6];
    const float* ffn_w    = (const float*)d_in[7];
    const float* ffn_b    = (const float*)d_in[8];
    float* out = (float*)d_out;

    // workspace layout (16B-aligned)
    unsigned short* Wh   = (unsigned short*)d_ws;            // N*HID bf16
    unsigned short* Wt   = Wh + (size_t)N_NODES * HID;       // 256*256 bf16
    unsigned short* Ft   = Wt + 65536;                       // 256*256 bf16
    float* s_src  = (float*)(Ft + 65536);                    // N*HEADS
    float* s_dst  = s_src + N_NODES * HEADS;                 // N*HEADS
    float* sorted_w = s_dst + N_NODES * HEADS;               // E*HEADS
    int*   counts = (int*)(sorted_w + (size_t)E_EDGES * HEADS); // N
    int*   offsets = counts + N_NODES;                       // N+1
    int*   cursor  = offsets + N_NODES + 1;                  // N
    int*   sorted_col = cursor + N_NODES;                    // E
    int*   bsum   = sorted_col + E_EDGES;                    // 128
    int*   bscan  = bsum + 128;                              // 128

    const int NB = (N_NODES + 511) / 512;                    // 98
    const int GRID_AGG = (N_NODES + 31) / 32;                // 1563

    hipMemsetAsync(counts, 0, N_NODES * sizeof(int), stream);
    prep_kernel<<<512, 256, 0, stream>>>(W, ffn_w, Wt, Ft);

    // Wh(bf16) = h(f32) @ W
    gemm_bres<true, false><<<256, 512, 0, stream>>>(h, Wt, nullptr, Wh, N_NODES);

    scores_kernel<<<N_NODES / 4, 256, 0, stream>>>(Wh, attn_fc, s_src, s_dst);
    hist_kernel<<<(E_EDGES + 255) / 256, 256, 0, stream>>>(erow, counts);
    scanA_kernel<<<NB, 256, 0, stream>>>(counts, bsum);
    scanB_kernel<<<1, 128, 0, stream>>>(bsum, bscan, NB);
    scanC_kernel<<<NB, 512, 0, stream>>>(counts, bscan, offsets, cursor);
    scatter_kernel<<<(E_EDGES + 255) / 256, 256, 0, stream>>>(
        erow, ecol, s_src, s_dst, cursor, sorted_col, (float4*)sorted_w);

    // fused: aggregate + residual + LN + FFN GEMM -> out (f32)
    agg_ffn_kernel<<<GRID_AGG, 512, 0, stream>>>(
        Wh, sorted_w, offsets, sorted_col, ln_gamma, ln_beta, Ft, ffn_b, out);
}

// Round 11
// 249.818 us; speedup vs baseline: 1.2391x; 1.2391x over previous
//
#include <hip/hip_runtime.h>
#include <hip/hip_bf16.h>

#define N_NODES 50000
#define E_EDGES 400000
#define IN_CH   256
#define HEADS   4
#define OUT_CH  64
#define HID     256
#define ALPHA   0.2f
#define LN_EPS  1e-5f

using f32x16 = __attribute__((ext_vector_type(16))) float;
using bf16x8 = __attribute__((ext_vector_type(8))) short;   // 8 bf16 (4 VGPRs)
using u16x8  = __attribute__((ext_vector_type(8))) unsigned short;
using u16x4  = __attribute__((ext_vector_type(4))) unsigned short;

typedef __attribute__((address_space(3))) void* lds_vp;
typedef const __attribute__((address_space(1))) void* gbl_vp;

__device__ __forceinline__ unsigned short f2bf(float f) {
    __hip_bfloat16 b = __float2bfloat16(f);
    return *(unsigned short*)&b;
}
__device__ __forceinline__ float bf2f(unsigned short u) {
    __hip_bfloat16 b = *(__hip_bfloat16*)&u;
    return __bfloat162float(b);
}

// ------------------------------------------------------------------ prep
__global__ __launch_bounds__(256) void prep_kernel(
    const float* __restrict__ W, const float* __restrict__ ffn_w,
    unsigned short* __restrict__ Wt, unsigned short* __restrict__ Ft)
{
    int i = blockIdx.x * 256 + threadIdx.x;
    if (i < 65536) {
        int n = i >> 8, k = i & 255;
        Wt[i] = f2bf(W[k * 256 + n]);
    } else {
        int j = i - 65536;
        int n = j >> 8, k = j & 255;
        Ft[j] = f2bf(ffn_w[k * 256 + n]);
    }
}

// ------------------------------------------------------------------ N-split B-resident GEMM
// C[M, colhalf*128 .. +128] = A[M,256] @ B[:, colhalf*128 .. +128].
// Bs = 128 rows of Bt x 256 k = 64 KiB -> 2 blocks/CU, 16 waves/CU (4/SIMD):
// 2x the TLP of the full-B design (R10 lesson: gather/stream phases live on
// occupancy).  Each wave independently streams a 32-row A strip, 2-deep
// register prefetch, 4x mfma_f32_32x32x16_bf16 per K-step, no barriers after
// the single stage barrier.  VGPR ~100 < 128 so launch_bounds(512,4) holds.
template<bool A_IS_F32, bool RELU_BIAS>
__global__ __launch_bounds__(512, 4) void gemm_bres(
    const void* __restrict__ Av, const unsigned short* __restrict__ Bt,
    const float* __restrict__ bias, void* __restrict__ Cv, int M)
{
    __shared__ unsigned short Bs[128 * 256];   // 64 KiB

    const int tid = threadIdx.x;
    const int lane = tid & 63, wid = tid >> 6;
    const int colhalf = blockIdx.x & 1;
    const int col0 = colhalf * 128;
    const int sb = blockIdx.x >> 1;            // 0..255

    // ---- stage half of B: linear LDS dest, inverse-swizzled global source
    #pragma unroll
    for (int i = 0; i < 8; i++) {
        int d = i * 512 + tid;                 // 16B-chunk id, 0..4095
        int n = d >> 5, cp = d & 31;           // local row n (0..127)
        int cs = cp ^ (n & 31);
        const unsigned short* g = Bt + (size_t)(col0 + n) * 256 + cs * 8;
        __builtin_amdgcn_global_load_lds((gbl_vp)g, (lds_vp)&Bs[(size_t)d * 8],
                                         16, 0, 0);
    }
    __syncthreads();

    const int strip = wid * 256 + sb;          // interleaved for CU balance
    const int r0 = strip * 32;
    if (r0 >= M) return;

    const int q5 = lane & 31, kg = lane >> 5;
    const int rowc = min(r0 + q5, M - 1);      // clamped for tail strip

    f32x16 acc[4] = {};

    const float* Af = (const float*)Av;
    const unsigned short* Ab = (const unsigned short*)Av;

    // ---- 2-deep A prefetch pipeline
    float4 pa[2], pb[2]; u16x8 pc[2];
    auto loadA = [&](int t, int slot) {
        if (A_IS_F32) {
            const float* p = Af + (size_t)rowc * 256 + t * 16 + kg * 8;
            pa[slot] = *(const float4*)p; pb[slot] = *(const float4*)(p + 4);
        } else {
            pc[slot] = *(const u16x8*)(Ab + (size_t)rowc * 256 + t * 16 + kg * 8);
        }
    };
    loadA(0, 0); loadA(1, 1);

    #pragma unroll
    for (int t = 0; t < 16; t++) {
        const int slot = t & 1;
        bf16x8 af;
        if (A_IS_F32) {
            union { unsigned int u[4]; bf16x8 v; } cv;
            cv.u[0] = (unsigned)f2bf(pa[slot].x) | ((unsigned)f2bf(pa[slot].y) << 16);
            cv.u[1] = (unsigned)f2bf(pa[slot].z) | ((unsigned)f2bf(pa[slot].w) << 16);
            cv.u[2] = (unsigned)f2bf(pb[slot].x) | ((unsigned)f2bf(pb[slot].y) << 16);
            cv.u[3] = (unsigned)f2bf(pb[slot].z) | ((unsigned)f2bf(pb[slot].w) << 16);
            af = cv.v;
        } else {
            union { u16x8 u; bf16x8 v; } cv; cv.u = pc[slot]; af = cv.v;
        }
        if (t + 2 < 16) loadA(t + 2, slot);    // refill consumed slot
        #pragma unroll
        for (int n = 0; n < 4; n++) {
            // B fragment: local row n*32+q5, k-chunk t*2+kg, swizzled (^q5)
            const bf16x8 bf = *(const bf16x8*)((const char*)Bs +
                (size_t)(n * 32 + q5) * 512 + (((t * 2 + kg) ^ q5) * 16));
            acc[n] = __builtin_amdgcn_mfma_f32_32x32x16_bf16(af, bf, acc[n], 0, 0, 0);
        }
    }

    // ---- epilogue.  D layout: col = lane&31, row = (reg&3)+8*(reg>>2)+4*kg
    #pragma unroll
    for (int n = 0; n < 4; n++) {
        int gc = col0 + n * 32 + q5;
        float bv = RELU_BIAS ? bias[gc] : 0.f;
        #pragma unroll
        for (int reg = 0; reg < 16; reg++) {
            int rl = (reg & 3) + 8 * (reg >> 2) + 4 * kg;
            int gr = r0 + rl;
            if (gr >= M) continue;
            float v = acc[n][reg];
            if (RELU_BIAS) {
                v += bv; v = v > 0.f ? v : 0.f;
                ((float*)Cv)[(size_t)gr * 256 + gc] = v;
            } else {
                ((unsigned short*)Cv)[(size_t)gr * 256 + gc] = f2bf(v);
            }
        }
    }
}

// ------------------------------------------------------------------ scores
__global__ __launch_bounds__(256) void scores_kernel(
    const unsigned short* __restrict__ Wh, const float* __restrict__ attn_fc,
    float* __restrict__ s_src, float* __restrict__ s_dst)
{
    const int lane = threadIdx.x & 63, wid = threadIdx.x >> 6;
    const int n = blockIdx.x * 4 + wid;
    const int h = lane >> 4;
    const int d0 = 4 * (lane & 15);
    u16x4 w = *(const u16x4*)(Wh + (size_t)n * HID + 4 * lane);
    float ps = 0.f, pd = 0.f;
    #pragma unroll
    for (int q = 0; q < 4; q++) {
        float wf = bf2f(w[q]);
        ps += wf * attn_fc[h * 128 + d0 + q];
        pd += wf * attn_fc[h * 128 + 64 + d0 + q];
    }
    #pragma unroll
    for (int off = 8; off; off >>= 1) {
        ps += __shfl_xor(ps, off, 16);
        pd += __shfl_xor(pd, off, 16);
    }
    if ((lane & 15) == 0) {
        s_src[n * HEADS + h] = ps;
        s_dst[n * HEADS + h] = pd;
    }
}

// ------------------------------------------------------------------ histogram
__global__ void hist_kernel(const int* __restrict__ erow, int* __restrict__ counts) {
    int e = blockIdx.x * blockDim.x + threadIdx.x;
    if (e < E_EDGES) atomicAdd(&counts[erow[e]], 1);
}

// ------------------------------------------------------------------ 3-pass scan
__global__ __launch_bounds__(256) void scanA_kernel(
    const int* __restrict__ counts, int* __restrict__ bsum)
{
    const int b = blockIdx.x, tid = threadIdx.x;
    int i0 = b * 512 + tid;
    int v = 0;
    if (i0 < N_NODES) v += counts[i0];
    if (i0 + 256 < N_NODES) v += counts[i0 + 256];
    #pragma unroll
    for (int off = 32; off; off >>= 1) v += __shfl_xor(v, off, 64);
    __shared__ int ws[4];
    if ((tid & 63) == 0) ws[tid >> 6] = v;
    __syncthreads();
    if (tid == 0) bsum[b] = ws[0] + ws[1] + ws[2] + ws[3];
}

__global__ __launch_bounds__(128) void scanB_kernel(
    const int* __restrict__ bsum, int* __restrict__ bscan, int nb)
{
    const int tid = threadIdx.x;
    const int lane = tid & 63, wid = tid >> 6;
    int val = (tid < nb) ? bsum[tid] : 0;
    int x = val;
    #pragma unroll
    for (int off = 1; off < 64; off <<= 1) {
        int y = __shfl_up(x, off, 64);
        if (lane >= off) x += y;
    }
    __shared__ int w0;
    if (tid == 63) w0 = x;
    __syncthreads();
    if (wid == 1) x += w0;
    if (tid < nb) bscan[tid] = x - val;
}

__global__ __launch_bounds__(512) void scanC_kernel(
    const int* __restrict__ counts, const int* __restrict__ bscan,
    int* __restrict__ offsets, int* __restrict__ cursor)
{
    const int b = blockIdx.x, tid = threadIdx.x;
    const int lane = tid & 63, wid = tid >> 6;
    const int i = b * 512 + tid;
    int v = (i < N_NODES) ? counts[i] : 0;
    int x = v;
    #pragma unroll
    for (int off = 1; off < 64; off <<= 1) {
        int y = __shfl_up(x, off, 64);
        if (lane >= off) x += y;
    }
    __shared__ int ws[8];
    if (lane == 63) ws[wid] = x;
    __syncthreads();
    if (wid == 0 && lane < 8) {
        int s = ws[lane];
        #pragma unroll
        for (int off = 1; off < 8; off <<= 1) {
            int y = __shfl_up(s, off, 8);
            if ((lane & 7) >= off) s += y;
        }
        ws[lane] = s;
    }
    __syncthreads();
    int prefix = (wid ? ws[wid - 1] : 0) + bscan[b];
    int excl = prefix + x - v;
    if (i < N_NODES) { offsets[i] = excl; cursor[i] = excl; }
    if (i == N_NODES - 1) offsets[N_NODES] = excl + v;
}

// ------------------------------------------------------------------ scatter + weight precompute
__global__ __launch_bounds__(256) void scatter_kernel(
    const int* __restrict__ erow, const int* __restrict__ ecol,
    const float* __restrict__ s_src, const float* __restrict__ s_dst,
    int* __restrict__ cursor, int* __restrict__ sorted_col,
    float4* __restrict__ sorted_w)
{
    int e = blockIdx.x * blockDim.x + threadIdx.x;
    if (e >= E_EDGES) return;
    int r = erow[e], c = ecol[e];
    float4 ss = ((const float4*)s_src)[r];
    float4 sd = ((const float4*)s_dst)[c];
    float sc[4] = {ss.x + sd.x, ss.y + sd.y, ss.z + sd.z, ss.w + sd.w};
    float4 w;
    float* wp = (float*)&w;
    #pragma unroll
    for (int h = 0; h < 4; h++) {
        float v = sc[h] > 0.f ? sc[h] : ALPHA * sc[h];
        wp[h] = __expf(v);
    }
    int pos = atomicAdd(&cursor[r], 1);
    sorted_col[pos] = c;
    sorted_w[pos] = w;
}

// ------------------------------------------------------------------ aggregate + residual + LN
// R7 structure (best measured, 41 µs): one wave per node, 2 edges in parallel
// via lane halves; lane owns 8 cols (u16x8 16B gather).
__global__ __launch_bounds__(256) void aggregate_ln_kernel(
    const unsigned short* __restrict__ Wh, const float* __restrict__ sorted_w,
    const int* __restrict__ offsets, const int* __restrict__ sorted_col,
    const float* __restrict__ ln_gamma, const float* __restrict__ ln_beta,
    unsigned short* __restrict__ h_ln)
{
    const int lane = threadIdx.x & 63, wid = threadIdx.x >> 6;
    const int n = blockIdx.x * 4 + wid;
    const int p = lane >> 5;
    const int q5 = lane & 31;
    const int c0 = q5 * 8;
    const int h = q5 >> 3;
    const int beg = offsets[n], end = offsets[n + 1];

    float acc[8] = {};
    float wsum = 0.f;
    for (int base = beg; base < end; base += 64) {
        int cnt = min(64, end - base);
        int cv = (base + lane < end) ? sorted_col[base + lane] : 0;
        int jj = 0;
        #pragma unroll 2
        for (; jj + 2 <= cnt; jj += 2) {
            int c = __shfl(cv, jj + p, 64);
            float w = sorted_w[(size_t)(base + jj + p) * 4 + h];
            u16x8 r = *(const u16x8*)(Wh + (size_t)c * HID + c0);
            wsum += w;
            #pragma unroll
            for (int k = 0; k < 8; k++) acc[k] += w * bf2f(r[k]);
        }
        if (jj < cnt) {                        // odd tail edge: half-wave 0 only
            int c = __shfl(cv, jj, 64);
            if (p == 0) {
                float w = sorted_w[(size_t)(base + jj) * 4 + h];
                u16x8 r = *(const u16x8*)(Wh + (size_t)c * HID + c0);
                wsum += w;
                #pragma unroll
                for (int k = 0; k < 8; k++) acc[k] += w * bf2f(r[k]);
            }
        }
    }
    wsum += __shfl_xor(wsum, 32, 64);
    #pragma unroll
    for (int k = 0; k < 8; k++) acc[k] += __shfl_xor(acc[k], 32, 64);

    u16x8 rr = *(const u16x8*)(Wh + (size_t)n * HID + c0);
    float inv_w = 1.f / (wsum + 1e-15f);
    float val[8];
    float s = 0.f;
    #pragma unroll
    for (int k = 0; k < 8; k++) {
        val[k] = acc[k] * inv_w + bf2f(rr[k]);
        s += val[k];
    }
    #pragma unroll
    for (int off = 16; off; off >>= 1) s += __shfl_xor(s, off, 64);
    float mu = s * (1.f / HID);
    float s2 = 0.f;
    #pragma unroll
    for (int k = 0; k < 8; k++) { float d = val[k] - mu; s2 += d * d; }
    #pragma unroll
    for (int off = 16; off; off >>= 1) s2 += __shfl_xor(s2, off, 64);
    float inv_std = rsqrtf(s2 * (1.f / HID) + LN_EPS);

    if (p == 0) {
        float4 g0 = *(const float4*)(ln_gamma + c0);
        float4 g1 = *(const float4*)(ln_gamma + c0 + 4);
        float4 b0 = *(const float4*)(ln_beta + c0);
        float4 b1 = *(const float4*)(ln_beta + c0 + 4);
        u16x8 outv;
        outv[0] = f2bf((val[0] - mu) * inv_std * g0.x + b0.x);
        outv[1] = f2bf((val[1] - mu) * inv_std * g0.y + b0.y);
        outv[2] = f2bf((val[2] - mu) * inv_std * g0.z + b0.z);
        outv[3] = f2bf((val[3] - mu) * inv_std * g0.w + b0.w);
        outv[4] = f2bf((val[4] - mu) * inv_std * g1.x + b1.x);
        outv[5] = f2bf((val[5] - mu) * inv_std * g1.y + b1.y);
        outv[6] = f2bf((val[6] - mu) * inv_std * g1.z + b1.z);
        outv[7] = f2bf((val[7] - mu) * inv_std * g1.w + b1.w);
        *(u16x8*)(h_ln + (size_t)n * HID + c0) = outv;
    }
}

// ------------------------------------------------------------------ launch
extern "C" void kernel_launch(void* const* d_in, const int* in_sizes, int n_in,
                              void* d_out, int out_size, void* d_ws, size_t ws_size,
                              hipStream_t stream)
{
    const float* h        = (const float*)d_in[0];
    const int*   erow     = (const int*)  d_in[1];
    const int*   ecol     = (const int*)  d_in[2];
    const float* W        = (const float*)d_in[3];
    const float* attn_fc  = (const float*)d_in[4];
    const float* ln_gamma = (const float*)d_in[5];
    const float* ln_beta  = (const float*)d_in[6];
    const float* ffn_w    = (const float*)d_in[7];
    const float* ffn_b    = (const float*)d_in[8];
    float* out = (float*)d_out;

    // workspace layout (16B-aligned)
    unsigned short* Wh   = (unsigned short*)d_ws;            // N*HID bf16
    unsigned short* h_ln = Wh + (size_t)N_NODES * HID;       // N*HID bf16
    unsigned short* Wt   = h_ln + (size_t)N_NODES * HID;     // 256*256 bf16
    unsigned short* Ft   = Wt + 65536;                       // 256*256 bf16
    float* s_src  = (float*)(Ft + 65536);                    // N*HEADS
    float* s_dst  = s_src + N_NODES * HEADS;                 // N*HEADS
    float* sorted_w = s_dst + N_NODES * HEADS;               // E*HEADS
    int*   counts = (int*)(sorted_w + (size_t)E_EDGES * HEADS); // N
    int*   offsets = counts + N_NODES;                       // N+1
    int*   cursor  = offsets + N_NODES + 1;                  // N
    int*   sorted_col = cursor + N_NODES;                    // E
    int*   bsum   = sorted_col + E_EDGES;                    // 128
    int*   bscan  = bsum + 128;                              // 128

    const int NB = (N_NODES + 511) / 512;                    // 98

    hipMemsetAsync(counts, 0, N_NODES * sizeof(int), stream);
    prep_kernel<<<512, 256, 0, stream>>>(W, ffn_w, Wt, Ft);

    // Wh(bf16) = h(f32) @ W   (N-split: 512 blocks, 2 col-halves)
    gemm_bres<true, false><<<512, 512, 0, stream>>>(h, Wt, nullptr, Wh, N_NODES);

    scores_kernel<<<N_NODES / 4, 256, 0, stream>>>(Wh, attn_fc, s_src, s_dst);
    hist_kernel<<<(E_EDGES + 255) / 256, 256, 0, stream>>>(erow, counts);
    scanA_kernel<<<NB, 256, 0, stream>>>(counts, bsum);
    scanB_kernel<<<1, 128, 0, stream>>>(bsum, bscan, NB);
    scanC_kernel<<<NB, 512, 0, stream>>>(counts, bscan, offsets, cursor);
    scatter_kernel<<<(E_EDGES + 255) / 256, 256, 0, stream>>>(
        erow, ecol, s_src, s_dst, cursor, sorted_col, (float4*)sorted_w);
    aggregate_ln_kernel<<<N_NODES / 4, 256, 0, stream>>>(
        Wh, sorted_w, offsets, sorted_col, ln_gamma, ln_beta, h_ln);

    // out(f32) = relu(h_ln(bf16) @ ffn_w + b)
    gemm_bres<false, true><<<512, 512, 0, stream>>>(h_ln, Ft, ffn_b, out, N_NODES);
}

// Round 13
// 248.360 us; speedup vs baseline: 1.2464x; 1.0059x over previous
//
#include <hip/hip_runtime.h>
#include <hip/hip_bf16.h>

#define N_NODES 50000
#define E_EDGES 400000
#define IN_CH   256
#define HEADS   4
#define OUT_CH  64
#define HID     256
#define ALPHA   0.2f
#define LN_EPS  1e-5f

using f32x16 = __attribute__((ext_vector_type(16))) float;
using bf16x8 = __attribute__((ext_vector_type(8))) short;   // 8 bf16 (4 VGPRs)
using u16x8  = __attribute__((ext_vector_type(8))) unsigned short;
using u16x4  = __attribute__((ext_vector_type(4))) unsigned short;

typedef __attribute__((address_space(3))) void* lds_vp;
typedef const __attribute__((address_space(1))) void* gbl_vp;

__device__ __forceinline__ unsigned short f2bf(float f) {
    __hip_bfloat16 b = __float2bfloat16(f);
    return *(unsigned short*)&b;
}
__device__ __forceinline__ float bf2f(unsigned short u) {
    __hip_bfloat16 b = *(__hip_bfloat16*)&u;
    return __bfloat162float(b);
}

// ------------------------------------------------------------------ prep
__global__ __launch_bounds__(256) void prep_kernel(
    const float* __restrict__ W, const float* __restrict__ ffn_w,
    unsigned short* __restrict__ Wt, unsigned short* __restrict__ Ft)
{
    int i = blockIdx.x * 256 + threadIdx.x;
    if (i < 65536) {
        int n = i >> 8, k = i & 255;
        Wt[i] = f2bf(W[k * 256 + n]);
    } else {
        int j = i - 65536;
        int n = j >> 8, k = j & 255;
        Ft[j] = f2bf(ffn_w[k * 256 + n]);
    }
}

// ------------------------------------------------------------------ N-split B-resident GEMM
// C[M, colhalf*128 .. +128] = A[M,256] @ B[:, colhalf*128 .. +128].
// Bs = 64 KiB -> 2 blocks/CU, 16 waves/CU.  Grid mapping: sb = bid&255,
// colhalf = bid>>8 so blocks b and b+256 (same A-panel) land on the SAME XCD
// (256 % 8 == 0) -> A fetched once per XCD L2.
// bf16-out path (GEMM1): C-write staged through the freed Bs as an LDS
// transpose -> u16x8 16B/lane stores (256B segments) instead of 64 scalar
// global_store_short (64B segments).
template<bool A_IS_F32, bool RELU_BIAS>
__global__ __launch_bounds__(512, 4) void gemm_bres(
    const void* __restrict__ Av, const unsigned short* __restrict__ Bt,
    const float* __restrict__ bias, void* __restrict__ Cv, int M)
{
    __shared__ unsigned short Bs[128 * 256];   // 64 KiB

    const int tid = threadIdx.x;
    const int lane = tid & 63, wid = tid >> 6;
    const int colhalf = blockIdx.x >> 8;       // XCD-pairing swizzle
    const int col0 = colhalf * 128;
    const int sb = blockIdx.x & 255;           // 0..255

    // ---- stage half of B: linear LDS dest, inverse-swizzled global source
    #pragma unroll
    for (int i = 0; i < 8; i++) {
        int d = i * 512 + tid;                 // 16B-chunk id, 0..4095
        int n = d >> 5, cp = d & 31;           // local row n (0..127)
        int cs = cp ^ (n & 31);
        const unsigned short* g = Bt + (size_t)(col0 + n) * 256 + cs * 8;
        __builtin_amdgcn_global_load_lds((gbl_vp)g, (lds_vp)&Bs[(size_t)d * 8],
                                         16, 0, 0);
    }
    __syncthreads();

    const int strip = wid * 256 + sb;          // interleaved for CU balance
    const int r0 = strip * 32;
    const bool active = (r0 < M);              // no early return: barriers below

    const int q5 = lane & 31, kg = lane >> 5;
    const int rowc = active ? min(r0 + q5, M - 1) : 0;

    f32x16 acc[4] = {};

    const float* Af = (const float*)Av;
    const unsigned short* Ab = (const unsigned short*)Av;

    // ---- 2-deep A prefetch pipeline
    float4 pa[2], pb[2]; u16x8 pc[2];
    auto loadA = [&](int t, int slot) {
        if (A_IS_F32) {
            const float* p = Af + (size_t)rowc * 256 + t * 16 + kg * 8;
            pa[slot] = *(const float4*)p; pb[slot] = *(const float4*)(p + 4);
        } else {
            pc[slot] = *(const u16x8*)(Ab + (size_t)rowc * 256 + t * 16 + kg * 8);
        }
    };

    if (active) {
        loadA(0, 0); loadA(1, 1);
        #pragma unroll
        for (int t = 0; t < 16; t++) {
            const int slot = t & 1;
            bf16x8 af;
            if (A_IS_F32) {
                union { unsigned int u[4]; bf16x8 v; } cv;
                cv.u[0] = (unsigned)f2bf(pa[slot].x) | ((unsigned)f2bf(pa[slot].y) << 16);
                cv.u[1] = (unsigned)f2bf(pa[slot].z) | ((unsigned)f2bf(pa[slot].w) << 16);
                cv.u[2] = (unsigned)f2bf(pb[slot].x) | ((unsigned)f2bf(pb[slot].y) << 16);
                cv.u[3] = (unsigned)f2bf(pb[slot].z) | ((unsigned)f2bf(pb[slot].w) << 16);
                af = cv.v;
            } else {
                union { u16x8 u; bf16x8 v; } cv; cv.u = pc[slot]; af = cv.v;
            }
            if (t + 2 < 16) loadA(t + 2, slot);
            #pragma unroll
            for (int n = 0; n < 4; n++) {
                const bf16x8 bf = *(const bf16x8*)((const char*)Bs +
                    (size_t)(n * 32 + q5) * 512 + (((t * 2 + kg) ^ q5) * 16));
                acc[n] = __builtin_amdgcn_mfma_f32_32x32x16_bf16(af, bf, acc[n], 0, 0, 0);
            }
        }
    }

    if (RELU_BIAS) {
        // f32 out: direct stores (128B segments per half-wave, coalesced)
        if (active) {
            #pragma unroll
            for (int n = 0; n < 4; n++) {
                int gc = col0 + n * 32 + q5;
                float bv = bias[gc];
                #pragma unroll
                for (int reg = 0; reg < 16; reg++) {
                    int rl = (reg & 3) + 8 * (reg >> 2) + 4 * kg;
                    int gr = r0 + rl;
                    if (gr >= M) continue;
                    float v = acc[n][reg] + bv;
                    v = v > 0.f ? v : 0.f;
                    ((float*)Cv)[(size_t)gr * 256 + gc] = v;
                }
            }
        }
    } else {
        // bf16 out: LDS-transpose epilogue through the freed Bs.
        __syncthreads();                       // all waves done reading Bs
        unsigned short* T = Bs + wid * 4096;   // 8 KiB per wave (32x128 u16)
        if (active) {
            #pragma unroll
            for (int n = 0; n < 4; n++) {
                #pragma unroll
                for (int reg = 0; reg < 16; reg++) {
                    int rl = (reg & 3) + 8 * (reg >> 2) + 4 * kg;
                    T[rl * 128 + n * 32 + q5] = f2bf(acc[n][reg]);
                }
            }
        }
        __syncthreads();                       // drain ds_writes (cross-lane)
        if (active) {
            #pragma unroll
            for (int i = 0; i < 8; i++) {
                int row = i * 4 + (lane >> 4);
                int cb = (lane & 15) * 8;
                u16x8 v = *(const u16x8*)(T + row * 128 + cb);
                int gr = r0 + row;
                if (gr < M)
                    *(u16x8*)((unsigned short*)Cv + (size_t)gr * 256 + col0 + cb) = v;
            }
        }
    }
}

// ------------------------------------------------------------------ scores
__global__ __launch_bounds__(256) void scores_kernel(
    const unsigned short* __restrict__ Wh, const float* __restrict__ attn_fc,
    float* __restrict__ s_src, float* __restrict__ s_dst)
{
    const int lane = threadIdx.x & 63, wid = threadIdx.x >> 6;
    const int n = blockIdx.x * 4 + wid;
    const int h = lane >> 4;
    const int d0 = 4 * (lane & 15);
    u16x4 w = *(const u16x4*)(Wh + (size_t)n * HID + 4 * lane);
    float ps = 0.f, pd = 0.f;
    #pragma unroll
    for (int q = 0; q < 4; q++) {
        float wf = bf2f(w[q]);
        ps += wf * attn_fc[h * 128 + d0 + q];
        pd += wf * attn_fc[h * 128 + 64 + d0 + q];
    }
    #pragma unroll
    for (int off = 8; off; off >>= 1) {
        ps += __shfl_xor(ps, off, 16);
        pd += __shfl_xor(pd, off, 16);
    }
    if ((lane & 15) == 0) {
        s_src[n * HEADS + h] = ps;
        s_dst[n * HEADS + h] = pd;
    }
}

// ------------------------------------------------------------------ histogram
__global__ void hist_kernel(const int* __restrict__ erow, int* __restrict__ counts) {
    int e = blockIdx.x * blockDim.x + threadIdx.x;
    if (e < E_EDGES) atomicAdd(&counts[erow[e]], 1);
}

// ------------------------------------------------------------------ 3-pass scan
__global__ __launch_bounds__(256) void scanA_kernel(
    const int* __restrict__ counts, int* __restrict__ bsum)
{
    const int b = blockIdx.x, tid = threadIdx.x;
    int i0 = b * 512 + tid;
    int v = 0;
    if (i0 < N_NODES) v += counts[i0];
    if (i0 + 256 < N_NODES) v += counts[i0 + 256];
    #pragma unroll
    for (int off = 32; off; off >>= 1) v += __shfl_xor(v, off, 64);
    __shared__ int ws[4];
    if ((tid & 63) == 0) ws[tid >> 6] = v;
    __syncthreads();
    if (tid == 0) bsum[b] = ws[0] + ws[1] + ws[2] + ws[3];
}

__global__ __launch_bounds__(128) void scanB_kernel(
    const int* __restrict__ bsum, int* __restrict__ bscan, int nb)
{
    const int tid = threadIdx.x;
    const int lane = tid & 63, wid = tid >> 6;
    int val = (tid < nb) ? bsum[tid] : 0;
    int x = val;
    #pragma unroll
    for (int off = 1; off < 64; off <<= 1) {
        int y = __shfl_up(x, off, 64);
        if (lane >= off) x += y;
    }
    __shared__ int w0;
    if (tid == 63) w0 = x;
    __syncthreads();
    if (wid == 1) x += w0;
    if (tid < nb) bscan[tid] = x - val;
}

__global__ __launch_bounds__(512) void scanC_kernel(
    const int* __restrict__ counts, const int* __restrict__ bscan,
    int* __restrict__ offsets, int* __restrict__ cursor)
{
    const int b = blockIdx.x, tid = threadIdx.x;
    const int lane = tid & 63, wid = tid >> 6;
    const int i = b * 512 + tid;
    int v = (i < N_NODES) ? counts[i] : 0;
    int x = v;
    #pragma unroll
    for (int off = 1; off < 64; off <<= 1) {
        int y = __shfl_up(x, off, 64);
        if (lane >= off) x += y;
    }
    __shared__ int ws[8];
    if (lane == 63) ws[wid] = x;
    __syncthreads();
    if (wid == 0 && lane < 8) {
        int s = ws[lane];
        #pragma unroll
        for (int off = 1; off < 8; off <<= 1) {
            int y = __shfl_up(s, off, 8);
            if ((lane & 7) >= off) s += y;
        }
        ws[lane] = s;
    }
    __syncthreads();
    int prefix = (wid ? ws[wid - 1] : 0) + bscan[b];
    int excl = prefix + x - v;
    if (i < N_NODES) { offsets[i] = excl; cursor[i] = excl; }
    if (i == N_NODES - 1) offsets[N_NODES] = excl + v;
}

// ------------------------------------------------------------------ scatter + weight precompute
__global__ __launch_bounds__(256) void scatter_kernel(
    const int* __restrict__ erow, const int* __restrict__ ecol,
    const float* __restrict__ s_src, const float* __restrict__ s_dst,
    int* __restrict__ cursor, int* __restrict__ sorted_col,
    float4* __restrict__ sorted_w)
{
    int e = blockIdx.x * blockDim.x + threadIdx.x;
    if (e >= E_EDGES) return;
    int r = erow[e], c = ecol[e];
    float4 ss = ((const float4*)s_src)[r];
    float4 sd = ((const float4*)s_dst)[c];
    float sc[4] = {ss.x + sd.x, ss.y + sd.y, ss.z + sd.z, ss.w + sd.w};
    float4 w;
    float* wp = (float*)&w;
    #pragma unroll
    for (int h = 0; h < 4; h++) {
        float v = sc[h] > 0.f ? sc[h] : ALPHA * sc[h];
        wp[h] = __expf(v);
    }
    int pos = atomicAdd(&cursor[r], 1);
    sorted_col[pos] = c;
    sorted_w[pos] = w;
}

// ------------------------------------------------------------------ aggregate + residual + LN
// R7 structure (best measured): one wave per node, 2 edges in parallel via
// lane halves; lane owns 8 cols (u16x8 16B gather).
__global__ __launch_bounds__(256) void aggregate_ln_kernel(
    const unsigned short* __restrict__ Wh, const float* __restrict__ sorted_w,
    const int* __restrict__ offsets, const int* __restrict__ sorted_col,
    const float* __restrict__ ln_gamma, const float* __restrict__ ln_beta,
    unsigned short* __restrict__ h_ln)
{
    const int lane = threadIdx.x & 63, wid = threadIdx.x >> 6;
    const int n = blockIdx.x * 4 + wid;
    const int p = lane >> 5;
    const int q5 = lane & 31;
    const int c0 = q5 * 8;
    const int h = q5 >> 3;
    const int beg = offsets[n], end = offsets[n + 1];

    float acc[8] = {};
    float wsum = 0.f;
    for (int base = beg; base < end; base += 64) {
        int cnt = min(64, end - base);
        int cv = (base + lane < end) ? sorted_col[base + lane] : 0;
        int jj = 0;
        #pragma unroll 2
        for (; jj + 2 <= cnt; jj += 2) {
            int c = __shfl(cv, jj + p, 64);
            float w = sorted_w[(size_t)(base + jj + p) * 4 + h];
            u16x8 r = *(const u16x8*)(Wh + (size_t)c * HID + c0);
            wsum += w;
            #pragma unroll
            for (int k = 0; k < 8; k++) acc[k] += w * bf2f(r[k]);
        }
        if (jj < cnt) {                        // odd tail edge: half-wave 0 only
            int c = __shfl(cv, jj, 64);
            if (p == 0) {
                float w = sorted_w[(size_t)(base + jj) * 4 + h];
                u16x8 r = *(const u16x8*)(Wh + (size_t)c * HID + c0);
                wsum += w;
                #pragma unroll
                for (int k = 0; k < 8; k++) acc[k] += w * bf2f(r[k]);
            }
        }
    }
    wsum += __shfl_xor(wsum, 32, 64);
    #pragma unroll
    for (int k = 0; k < 8; k++) acc[k] += __shfl_xor(acc[k], 32, 64);

    u16x8 rr = *(const u16x8*)(Wh + (size_t)n * HID + c0);
    float inv_w = 1.f / (wsum + 1e-15f);
    float val[8];
    float s = 0.f;
    #pragma unroll
    for (int k = 0; k < 8; k++) {
        val[k] = acc[k] * inv_w + bf2f(rr[k]);
        s += val[k];
    }
    #pragma unroll
    for (int off = 16; off; off >>= 1) s += __shfl_xor(s, off, 64);
    float mu = s * (1.f / HID);
    float s2 = 0.f;
    #pragma unroll
    for (int k = 0; k < 8; k++) { float d = val[k] - mu; s2 += d * d; }
    #pragma unroll
    for (int off = 16; off; off >>= 1) s2 += __shfl_xor(s2, off, 64);
    float inv_std = rsqrtf(s2 * (1.f / HID) + LN_EPS);

    if (p == 0) {
        float4 g0 = *(const float4*)(ln_gamma + c0);
        float4 g1 = *(const float4*)(ln_gamma + c0 + 4);
        float4 b0 = *(const float4*)(ln_beta + c0);
        float4 b1 = *(const float4*)(ln_beta + c0 + 4);
        u16x8 outv;
        outv[0] = f2bf((val[0] - mu) * inv_std * g0.x + b0.x);
        outv[1] = f2bf((val[1] - mu) * inv_std * g0.y + b0.y);
        outv[2] = f2bf((val[2] - mu) * inv_std * g0.z + b0.z);
        outv[3] = f2bf((val[3] - mu) * inv_std * g0.w + b0.w);
        outv[4] = f2bf((val[4] - mu) * inv_std * g1.x + b1.x);
        outv[5] = f2bf((val[5] - mu) * inv_std * g1.y + b1.y);
        outv[6] = f2bf((val[6] - mu) * inv_std * g1.z + b1.z);
        outv[7] = f2bf((val[7] - mu) * inv_std * g1.w + b1.w);
        *(u16x8*)(h_ln + (size_t)n * HID + c0) = outv;
    }
}

// ------------------------------------------------------------------ launch
extern "C" void kernel_launch(void* const* d_in, const int* in_sizes, int n_in,
                              void* d_out, int out_size, void* d_ws, size_t ws_size,
                              hipStream_t stream)
{
    const float* h        = (const float*)d_in[0];
    const int*   erow     = (const int*)  d_in[1];
    const int*   ecol     = (const int*)  d_in[2];
    const float* W        = (const float*)d_in[3];
    const float* attn_fc  = (const float*)d_in[4];
    const float* ln_gamma = (const float*)d_in[5];
    const float* ln_beta  = (const float*)d_in[6];
    const float* ffn_w    = (const float*)d_in[7];
    const float* ffn_b    = (const float*)d_in[8];
    float* out = (float*)d_out;

    // workspace layout (16B-aligned)
    unsigned short* Wh   = (unsigned short*)d_ws;            // N*HID bf16
    unsigned short* h_ln = Wh + (size_t)N_NODES * HID;       // N*HID bf16
    unsigned short* Wt   = h_ln + (size_t)N_NODES * HID;     // 256*256 bf16
    unsigned short* Ft   = Wt + 65536;                       // 256*256 bf16
    float* s_src  = (float*)(Ft + 65536);                    // N*HEADS
    float* s_dst  = s_src + N_NODES * HEADS;                 // N*HEADS
    float* sorted_w = s_dst + N_NODES * HEADS;               // E*HEADS
    int*   counts = (int*)(sorted_w + (size_t)E_EDGES * HEADS); // N
    int*   offsets = counts + N_NODES;                       // N+1
    int*   cursor  = offsets + N_NODES + 1;                  // N
    int*   sorted_col = cursor + N_NODES;                    // E
    int*   bsum   = sorted_col + E_EDGES;                    // 128
    int*   bscan  = bsum + 128;                              // 128

    const int NB = (N_NODES + 511) / 512;                    // 98

    hipMemsetAsync(counts, 0, N_NODES * sizeof(int), stream);
    prep_kernel<<<512, 256, 0, stream>>>(W, ffn_w, Wt, Ft);

    // Wh(bf16) = h(f32) @ W   (N-split, XCD-paired col halves)
    gemm_bres<true, false><<<512, 512, 0, stream>>>(h, Wt, nullptr, Wh, N_NODES);

    scores_kernel<<<N_NODES / 4, 256, 0, stream>>>(Wh, attn_fc, s_src, s_dst);
    hist_kernel<<<(E_EDGES + 255) / 256, 256, 0, stream>>>(erow, counts);
    scanA_kernel<<<NB, 256, 0, stream>>>(counts, bsum);
    scanB_kernel<<<1, 128, 0, stream>>>(bsum, bscan, NB);
    scanC_kernel<<<NB, 512, 0, stream>>>(counts, bscan, offsets, cursor);
    scatter_kernel<<<(E_EDGES + 255) / 256, 256, 0, stream>>>(
        erow, ecol, s_src, s_dst, cursor, sorted_col, (float4*)sorted_w);
    aggregate_ln_kernel<<<N_NODES / 4, 256, 0, stream>>>(
        Wh, sorted_w, offsets, sorted_col, ln_gamma, ln_beta, h_ln);

    // out(f32) = relu(h_ln(bf16) @ ffn_w + b)
    gemm_bres<false, true><<<512, 512, 0, stream>>>(h_ln, Ft, ffn_b, out, N_NODES);
}